// Round 6
// baseline (450.000 us; speedup 1.0000x reference)
//
#include <hip/hip_runtime.h>

#define N_NODES 100000
#define D_IN 128
#define D_OUT 256            // OUT_CH * HEADS
#define NBLK 512             // coarse-pass blocks (2 rows/thread in scan)
#define NBKT 2048            // bucket array size (1563 used)
#define BSH  6               // bucket = dst >> 6  (64 nodes / bucket)
#define BNODES 64
#define NBUCKETS ((N_NODES + BNODES - 1) / BNODES)   // 1563
#define CAP  3072            // max edges per bucket in LDS (mean 2048, +22 sigma)

typedef __attribute__((ext_vector_type(8))) short short8_t;  // 8 bf16
typedef __attribute__((ext_vector_type(4))) float f32x4;

__device__ inline unsigned short f2bf_rne(float f) {
    unsigned u = __float_as_uint(f);
    u += 0x7fffu + ((u >> 16) & 1u);
    return (unsigned short)(u >> 16);
}

// ---------------------------------------------------------------------------
// x (fp32) -> xb (bf16 as ushort)
// ---------------------------------------------------------------------------
__global__ __launch_bounds__(256) void convert_kernel(
    const float* __restrict__ x, ushort* __restrict__ xb, int n4)
{
    int i = blockIdx.x * 256 + threadIdx.x;
    if (i < n4) {
        float4 v = ((const float4*)x)[i];
        ushort4 r;
        r.x = f2bf_rne(v.x); r.y = f2bf_rne(v.y);
        r.z = f2bf_rne(v.z); r.w = f2bf_rne(v.w);
        ((ushort4*)xb)[i] = r;
    }
}

// ---------------------------------------------------------------------------
// W (fp32 [128][256]) -> wfrag: MFMA B-fragment order, bf16.
// frag index fi = ks*16+nt (ks: K-step of 32, nt: 16-col tile).
// lane l, elem e  <->  B[k][n], k = ks*32 + (l>>4)*8 + e, n = nt*16 + (l&15).
// ---------------------------------------------------------------------------
__global__ __launch_bounds__(256) void wfrag_kernel(
    const float* __restrict__ W, short8_t* __restrict__ wfrag)
{
    int tid  = blockIdx.x * 256 + threadIdx.x;   // 4096 frags total
    int lane = tid & 63;
    int fi   = tid >> 6;                          // 0..63
    int ks   = fi >> 4, nt = fi & 15;
    int k0   = ks * 32 + (lane >> 4) * 8;
    int col  = nt * 16 + (lane & 15);
    short8_t v;
    #pragma unroll
    for (int e = 0; e < 8; e++)
        v[e] = (short)f2bf_rne(W[(size_t)(k0 + e) * D_OUT + col]);
    wfrag[tid] = v;
}

// ---------------------------------------------------------------------------
// Coarse pass 1: per-block LDS histogram of buckets
// ---------------------------------------------------------------------------
__global__ __launch_bounds__(256) void binA_hist(
    const int* __restrict__ dst, int* __restrict__ blockHist, int E, int chunk)
{
    __shared__ int h[NBKT];
    int b = blockIdx.x, t = threadIdx.x;
    for (int i = t; i < NBKT; i += 256) h[i] = 0;
    __syncthreads();
    int e0 = b * chunk, e1 = min(e0 + chunk, E);
    for (int e = e0 + t; e < e1; e += 256)
        atomicAdd(&h[dst[e] >> BSH], 1);
    __syncthreads();
    for (int i = t; i < NBKT; i += 256)
        blockHist[b * NBKT + i] = h[i];
}

// ---------------------------------------------------------------------------
// Coarse pass 2a: per-bucket exclusive scan over NBLK=512 blocks (2 rows per
// thread), in place; bucketTotal[bucket] = column sum.
// ---------------------------------------------------------------------------
__global__ __launch_bounds__(256) void binA_scan(
    int* __restrict__ blockHist, int* __restrict__ bucketTotal)
{
    __shared__ int wsum[4];
    int bucket = blockIdx.x;
    int t = threadIdx.x, lane = t & 63, w = t >> 6;
    int v0 = blockHist[(t * 2    ) * NBKT + bucket];
    int v1 = blockHist[(t * 2 + 1) * NBKT + bucket];
    int v = v0 + v1;
    int s = v;
    #pragma unroll
    for (int d = 1; d < 64; d <<= 1) {
        int u = __shfl_up(s, d);
        if (lane >= d) s += u;
    }
    if (lane == 63) wsum[w] = s;
    __syncthreads();
    int wo = 0;
    for (int j = 0; j < w; j++) wo += wsum[j];
    int excl = wo + s - v;
    blockHist[(t * 2    ) * NBKT + bucket] = excl;
    blockHist[(t * 2 + 1) * NBKT + bucket] = excl + v0;
    if (t == 255) {
        int tot = 0;
        for (int j = 0; j < 4; j++) tot += wsum[j];
        bucketTotal[bucket] = tot;
    }
}

// ---------------------------------------------------------------------------
// Coarse pass 2b: exclusive scan of bucketTotal[2048] -> bucketBase[2048]
// (8 entries per thread)
// ---------------------------------------------------------------------------
__global__ __launch_bounds__(256) void binA_scanbase(
    const int* __restrict__ bucketTotal, int* __restrict__ bucketBase)
{
    __shared__ int wsum[4];
    int t = threadIdx.x, lane = t & 63, w = t >> 6;
    int i0 = t * 8;
    int a[8], v = 0;
    #pragma unroll
    for (int j = 0; j < 8; j++) { a[j] = bucketTotal[i0 + j]; v += a[j]; }
    int s = v;
    #pragma unroll
    for (int d = 1; d < 64; d <<= 1) {
        int u = __shfl_up(s, d);
        if (lane >= d) s += u;
    }
    if (lane == 63) wsum[w] = s;
    __syncthreads();
    int wo = 0;
    for (int j = 0; j < w; j++) wo += wsum[j];
    int excl = wo + s - v;
    #pragma unroll
    for (int j = 0; j < 8; j++) { bucketBase[i0 + j] = excl; excl += a[j]; }
}

// ---------------------------------------------------------------------------
// Coarse pass 3: scatter packed (dstLocal<<17 | src) into bucket regions.
// ---------------------------------------------------------------------------
__global__ __launch_bounds__(256) void binA_scatter(
    const int* __restrict__ src, const int* __restrict__ dst,
    const int* __restrict__ blockHist, const int* __restrict__ bucketBase,
    unsigned* __restrict__ pairs, int E, int chunk)
{
    __shared__ int offs[NBKT];
    int b = blockIdx.x, t = threadIdx.x;
    for (int i = t; i < NBKT; i += 256)
        offs[i] = bucketBase[i] + blockHist[b * NBKT + i];
    __syncthreads();
    int e0 = b * chunk, e1 = min(e0 + chunk, E);
    for (int e = e0 + t; e < e1; e += 256) {
        int d = dst[e];
        int bin = d >> BSH;
        int pos = atomicAdd(&offs[bin], 1);
        pairs[pos] = ((unsigned)(d & (BNODES - 1)) << 17) | (unsigned)src[e];
    }
}

// ---------------------------------------------------------------------------
// Merged fused kernel: per 64-node bucket —
//   (1) LDS counting sort of the bucket's pairs (2 coalesced passes over the
//       L2-resident pairs segment, no global rewrite, no offs/deg arrays),
//   (2) gather-aggregate (round-5-proven readlane row-gather, ids from LDS),
//   (3) MFMA linear epilogue (round-5-proven fragment layout, 64 rows).
// LDS ~29.5 KB -> 5 blocks/CU.
// ---------------------------------------------------------------------------
template <bool USE_BF16>
__global__ __launch_bounds__(256) void fused_kernel(
    const float* __restrict__ x,
    const ushort* __restrict__ xb,
    const unsigned* __restrict__ pairs,
    const int* __restrict__ bucketBase,
    const short8_t* __restrict__ wfrag,
    const float* __restrict__ b,
    float* __restrict__ out)
{
    __shared__ int srcSorted[CAP];                    // 12 KB
    __shared__ __align__(16) ushort shb[BNODES * D_IN]; // 16 KB bf16 h, swizzled
    __shared__ int hist_l[BNODES];
    __shared__ int offs_l[BNODES];
    __shared__ int rank_l[BNODES];

    const int t    = threadIdx.x;
    const int lane = t & 63;
    const int w    = t >> 6;
    const int bkt  = blockIdx.x;
    const int n0   = bkt << BSH;

    const int e0 = bucketBase[bkt], e1 = bucketBase[bkt + 1];
    int cnt = e1 - e0;
    if (cnt > CAP) cnt = CAP;   // statistically unreachable (mean+22 sigma)

    if (t < BNODES) hist_l[t] = 0;
    __syncthreads();

    // --- pass 1: histogram ---
    for (int i = t; i < cnt; i += 256)
        atomicAdd(&hist_l[pairs[e0 + i] >> 17], 1);
    __syncthreads();

    // --- wave-0 exclusive scan of 64 bins ---
    if (t < 64) {
        int v = hist_l[t];
        int s = v;
        #pragma unroll
        for (int d = 1; d < 64; d <<= 1) {
            int u = __shfl_up(s, d);
            if (t >= d) s += u;
        }
        offs_l[t] = s - v;
        rank_l[t] = s - v;
    }
    __syncthreads();

    // --- pass 2: scatter src into LDS sorted order ---
    for (int i = t; i < cnt; i += 256) {
        unsigned p = pairs[e0 + i];
        int pos = atomicAdd(&rank_l[p >> 17], 1);
        srcSorted[pos] = (int)(p & 0x1FFFFu);
    }
    __syncthreads();

    // --- gather-aggregate: wave w owns rows w*16 .. w*16+15 ---
    for (int nn = 0; nn < 16; nn++) {
        int nl = (w << 4) + nn;
        int n  = n0 + nl;
        int start = offs_l[nl];
        int d     = hist_l[nl];
        float accx = 0.0f, accy = 0.0f;
        for (int base = 0; base < d; base += 64) {
            int m = d - base; if (m > 64) m = 64;
            int id = (lane < m) ? srcSorted[start + base + lane] : 0;
            int j = 0;
            for (; j + 4 <= m; j += 4) {
                int s0 = __builtin_amdgcn_readlane(id, j);
                int s1 = __builtin_amdgcn_readlane(id, j + 1);
                int s2 = __builtin_amdgcn_readlane(id, j + 2);
                int s3 = __builtin_amdgcn_readlane(id, j + 3);
                if (USE_BF16) {
                    ushort2 u0 = ((const ushort2*)(xb + (size_t)s0 * D_IN))[lane];
                    ushort2 u1 = ((const ushort2*)(xb + (size_t)s1 * D_IN))[lane];
                    ushort2 u2 = ((const ushort2*)(xb + (size_t)s2 * D_IN))[lane];
                    ushort2 u3 = ((const ushort2*)(xb + (size_t)s3 * D_IN))[lane];
                    accx += __uint_as_float((unsigned)u0.x << 16)
                          + __uint_as_float((unsigned)u1.x << 16)
                          + __uint_as_float((unsigned)u2.x << 16)
                          + __uint_as_float((unsigned)u3.x << 16);
                    accy += __uint_as_float((unsigned)u0.y << 16)
                          + __uint_as_float((unsigned)u1.y << 16)
                          + __uint_as_float((unsigned)u2.y << 16)
                          + __uint_as_float((unsigned)u3.y << 16);
                } else {
                    float2 v0 = ((const float2*)(x + (size_t)s0 * D_IN))[lane];
                    float2 v1 = ((const float2*)(x + (size_t)s1 * D_IN))[lane];
                    float2 v2 = ((const float2*)(x + (size_t)s2 * D_IN))[lane];
                    float2 v3 = ((const float2*)(x + (size_t)s3 * D_IN))[lane];
                    accx += v0.x + v1.x + v2.x + v3.x;
                    accy += v0.y + v1.y + v2.y + v3.y;
                }
            }
            for (; j < m; j++) {
                int s0 = __builtin_amdgcn_readlane(id, j);
                if (USE_BF16) {
                    ushort2 u0 = ((const ushort2*)(xb + (size_t)s0 * D_IN))[lane];
                    accx += __uint_as_float((unsigned)u0.x << 16);
                    accy += __uint_as_float((unsigned)u0.y << 16);
                } else {
                    float2 v0 = ((const float2*)(x + (size_t)s0 * D_IN))[lane];
                    accx += v0.x; accy += v0.y;
                }
            }
        }
        float hx = 0.0f, hy = 0.0f;
        if (n < N_NODES) {
            float invc = 1.0f / ((float)d + 1e-8f);
            float2 xv = ((const float2*)(x + (size_t)n * D_IN))[lane];
            hx = xv.x + accx * invc;
            hy = xv.y + accy * invc;
        }
        unsigned hp = ((unsigned)f2bf_rne(hy) << 16) | (unsigned)f2bf_rne(hx);
        unsigned byteoff = ((unsigned)(nl * 256 + lane * 4)) ^ (((unsigned)nl & 7u) << 4);
        *(unsigned*)((char*)shb + byteoff) = hp;
    }
    __syncthreads();

    // ---- MFMA epilogue: wave w owns rows w*16..+15, all 16 col-tiles ----
    const int r  = lane & 15;
    const int hi = lane >> 4;
    const int rr = (w << 4) + r;

    short8_t afrag[4];
    #pragma unroll
    for (int ks = 0; ks < 4; ks++) {
        unsigned aoff = ((unsigned)(rr * 256 + ks * 64 + hi * 16)) ^ (((unsigned)rr & 7u) << 4);
        afrag[ks] = *(const short8_t*)((const char*)shb + aoff);
    }

    #pragma unroll 4
    for (int nt = 0; nt < 16; nt++) {
        f32x4 acc = {0.0f, 0.0f, 0.0f, 0.0f};
        #pragma unroll
        for (int ks = 0; ks < 4; ks++) {
            short8_t bf = wfrag[(ks * 16 + nt) * 64 + lane];
            acc = __builtin_amdgcn_mfma_f32_16x16x32_bf16(afrag[ks], bf, acc, 0, 0, 0);
        }
        int col = nt * 16 + r;
        float bias = b[col];
        #pragma unroll
        for (int reg = 0; reg < 4; reg++) {
            int node = n0 + (w << 4) + hi * 4 + reg;
            if (node < N_NODES)
                out[(size_t)node * D_OUT + col] = acc[reg] + bias;
        }
    }
}

extern "C" void kernel_launch(void* const* d_in, const int* in_sizes, int n_in,
                              void* d_out, int out_size, void* d_ws, size_t ws_size,
                              hipStream_t stream)
{
    const float* x  = (const float*)d_in[0];
    const int*   ei = (const int*)d_in[1];   // [2,E] int32: row0=src, row1=dst
    const float* W  = (const float*)d_in[2];
    const float* b  = (const float*)d_in[3];
    float*       out = (float*)d_out;

    const int E = in_sizes[1] / 2;
    const int* src = ei;
    const int* dst = ei + E;
    const int chunk = (E + NBLK - 1) / NBLK;

    const size_t xb_bytes   = (size_t)N_NODES * D_IN * 2;     // 25.6 MB
    const size_t pairs_b    = (size_t)E * 4;                  // 12.8 MB
    const size_t bh_b       = (size_t)NBLK * NBKT * 4;        // 4 MB
    const size_t small_b    = (size_t)NBKT * 4;               // 8 KB each
    const size_t wf_b       = (size_t)4096 * 16;              // 64 KB
    const size_t need_bf16  = xb_bytes + pairs_b + bh_b + 2 * small_b + wf_b;
    const bool use_bf16 = (ws_size >= need_bf16);

    char* p = (char*)d_ws;
    ushort* xb = nullptr;
    if (use_bf16) { xb = (ushort*)p; p += xb_bytes; }
    unsigned* pairs  = (unsigned*)p;  p += pairs_b;
    int* blockHist   = (int*)p;       p += bh_b;
    int* bucketTotal = (int*)p;       p += small_b;
    int* bucketBase  = (int*)p;       p += small_b;
    short8_t* wfrag  = (short8_t*)p;

    if (use_bf16) {
        int n4 = N_NODES * D_IN / 4;
        convert_kernel<<<dim3((n4 + 255) / 256), dim3(256), 0, stream>>>(x, xb, n4);
    }
    wfrag_kernel<<<dim3(16), dim3(256), 0, stream>>>(W, wfrag);

    binA_hist    <<<dim3(NBLK), dim3(256), 0, stream>>>(dst, blockHist, E, chunk);
    binA_scan    <<<dim3(NBKT), dim3(256), 0, stream>>>(blockHist, bucketTotal);
    binA_scanbase<<<dim3(1),    dim3(256), 0, stream>>>(bucketTotal, bucketBase);
    binA_scatter <<<dim3(NBLK), dim3(256), 0, stream>>>(
        src, dst, blockHist, bucketBase, pairs, E, chunk);

    if (use_bf16)
        fused_kernel<true><<<dim3(NBUCKETS), dim3(256), 0, stream>>>(
            x, xb, pairs, bucketBase, wfrag, b, out);
    else
        fused_kernel<false><<<dim3(NBUCKETS), dim3(256), 0, stream>>>(
            x, xb, pairs, bucketBase, wfrag, b, out);
}